// Round 2
// baseline (1315.834 us; speedup 1.0000x reference)
//
#include <hip/hip_runtime.h>
#include <hip/hip_bf16.h>

#define NN 60000
#define NE 600000
#define DD 128

// ---- degree (edges only; +1 self-loop added in dinv) ----
__global__ __launch_bounds__(256) void deg_kernel(const int* __restrict__ dst, int* __restrict__ deg) {
    int e = blockIdx.x * 256 + threadIdx.x;
    if (e < NE) atomicAdd(&deg[dst[e]], 1);
}

__global__ __launch_bounds__(256) void dinv_kernel(const int* __restrict__ deg, float* __restrict__ dinv) {
    int i = blockIdx.x * 256 + threadIdx.x;
    if (i < NN) dinv[i] = rsqrtf((float)(deg[i] + 1));
}

// ---- simple GEMM: C[60000x128] = A[60000x128] @ W[128x128], W fp32 in LDS ----
// block = 256 threads, 32 rows per block. thread: col j = tid&127, rg = tid>>7,
// rows rg, rg+2, ..., rg+30 (16 rows). LDS = 64KB (W) + 16KB (A tile) = 80KB.
__global__ __launch_bounds__(256) void gemm_kernel(const float* __restrict__ A,
                                                   const float* __restrict__ W,
                                                   float* __restrict__ C) {
    __shared__ float wl[DD * DD];   // 64KB
    __shared__ float al[32 * DD];   // 16KB
    int tid = threadIdx.x;
    for (int i = tid; i < DD * DD; i += 256) wl[i] = W[i];
    int rbase = blockIdx.x * 32;
    const float* Ab = A + (size_t)rbase * DD;
    for (int i = tid; i < 32 * DD; i += 256) al[i] = Ab[i];
    __syncthreads();

    int j = tid & 127;
    int rg = tid >> 7;  // 0..1
    float acc[16];
#pragma unroll
    for (int i = 0; i < 16; i++) acc[i] = 0.f;
    for (int k = 0; k < DD; k++) {
        float wv = wl[k * DD + j];
#pragma unroll
        for (int i = 0; i < 16; i++) acc[i] += al[(rg + 2 * i) * DD + k] * wv;
    }
    float* Cb = C + (size_t)rbase * DD;
#pragma unroll
    for (int i = 0; i < 16; i++) Cb[(size_t)(rg + 2 * i) * DD + j] = acc[i];
}

// ---- scatter-aggregate: one wave (64 lanes) per edge, 2 features per lane ----
// items [0,NE): real edges. items [NE, NE+NN): self-loops (s=t=item-NE).
__global__ __launch_bounds__(256) void scatter_kernel(const float* __restrict__ xw,
                                                      const float* __restrict__ dinv,
                                                      const int* __restrict__ src,
                                                      const int* __restrict__ dst,
                                                      float* __restrict__ agg) {
    int wid = (int)((blockIdx.x * 256 + threadIdx.x) >> 6);
    int lane = threadIdx.x & 63;
    if (wid >= NE + NN) return;
    int s, t;
    if (wid < NE) { s = src[wid]; t = dst[wid]; }
    else { s = t = wid - NE; }
    float c = dinv[s] * dinv[t];
    const float* xr = xw + (size_t)s * DD;
    float* ar = agg + (size_t)t * DD;
    atomicAdd(&ar[lane], xr[lane] * c);
    atomicAdd(&ar[lane + 64], xr[lane + 64] * c);
}

// ---- batchnorm stats: sums[0..127]=sum, sums[128..255]=sumsq ----
__global__ __launch_bounds__(256) void bnstat_kernel(const float* __restrict__ h, float* __restrict__ sums) {
    int d = threadIdx.x & 127;
    int rg = threadIdx.x >> 7;  // 0..1
    int r0 = blockIdx.x * 256 + rg;
    float s = 0.f, q = 0.f;
    for (int i = 0; i < 128; i++) {
        int r = r0 + 2 * i;
        if (r < NN) {
            float v = h[(size_t)r * DD + d];
            s += v;
            q += v * v;
        }
    }
    __shared__ float ls[256], lq[256];
    ls[threadIdx.x] = s;
    lq[threadIdx.x] = q;
    __syncthreads();
    if (threadIdx.x < 128) {
        s = ls[threadIdx.x] + ls[threadIdx.x + 128];
        q = lq[threadIdx.x] + lq[threadIdx.x + 128];
        atomicAdd(&sums[d], s);
        atomicAdd(&sums[128 + d], q);
    }
}

// ---- normalize + affine + leaky-relu. GCN bias b omitted: a per-feature
// constant shift cancels exactly in BatchNorm (shifts mu identically). ----
__global__ __launch_bounds__(256) void bnapply_kernel(const float* __restrict__ h,
                                                      const float* __restrict__ sums,
                                                      const float* __restrict__ g,
                                                      const float* __restrict__ be,
                                                      float* __restrict__ out,
                                                      int act) {
    int idx = blockIdx.x * 256 + threadIdx.x;
    if (idx >= NN * DD) return;
    int d = idx & 127;
    const float invN = 1.0f / (float)NN;
    float mu = sums[d] * invN;
    float var = sums[128 + d] * invN - mu * mu;
    float inv = rsqrtf(var + 1e-5f);
    float v = (h[idx] - mu) * inv * g[d] + be[d];
    if (act) v = (v >= 0.f) ? v : 0.01f * v;
    out[idx] = v;
}

extern "C" void kernel_launch(void* const* d_in, const int* in_sizes, int n_in,
                              void* d_out, int out_size, void* d_ws, size_t ws_size,
                              hipStream_t stream) {
    const float* x = (const float*)d_in[0];
    const int* ei = (const int*)d_in[1];
    const int* srcp = ei;
    const int* dstp = ei + NE;
    const float* w[3]  = {(const float*)d_in[2], (const float*)d_in[6],  (const float*)d_in[10]};
    const float* g[3]  = {(const float*)d_in[4], (const float*)d_in[8],  (const float*)d_in[12]};
    const float* be[3] = {(const float*)d_in[5], (const float*)d_in[9],  (const float*)d_in[13]};

    // workspace: A (xw) + B (h) + deg + dinv + sums  ~= 62 MB
    float* bufA = (float*)d_ws;                       // xw
    float* bufB = bufA + (size_t)NN * DD;             // h / agg
    int* deg = (int*)(bufB + (size_t)NN * DD);
    float* dinv = (float*)(deg + NN);
    float* sums = dinv + NN;  // 256 floats
    float* out = (float*)d_out;

    hipMemsetAsync(deg, 0, NN * sizeof(int), stream);
    deg_kernel<<<(NE + 255) / 256, 256, 0, stream>>>(dstp, deg);
    dinv_kernel<<<(NN + 255) / 256, 256, 0, stream>>>(deg, dinv);

    for (int L = 0; L < 3; ++L) {
        const float* in = (L == 0) ? x : bufB;
        gemm_kernel<<<NN / 32, 256, 0, stream>>>(in, w[L], bufA);
        // gemm has fully consumed bufB (stream-ordered), safe to reuse as agg
        hipMemsetAsync(bufB, 0, (size_t)NN * DD * sizeof(float), stream);
        hipMemsetAsync(sums, 0, 256 * sizeof(float), stream);
        scatter_kernel<<<(NE + NN + 3) / 4, 256, 0, stream>>>(bufA, dinv, srcp, dstp, bufB);
        bnstat_kernel<<<(NN + 255) / 256, 256, 0, stream>>>(bufB, sums);
        int last = (L == 2);
        bnapply_kernel<<<(NN * DD + 255) / 256, 256, 0, stream>>>(
            bufB, sums, g[L], be[L], last ? out : bufB, last ? 0 : 1);
    }
}